// Round 15
// baseline (252.852 us; speedup 1.0000x reference)
//
#include <hip/hip_runtime.h>
#include <hip/hip_bf16.h>

typedef unsigned int u32;
typedef unsigned short u16;
typedef __bf16 bf16x8 __attribute__((ext_vector_type(8)));
typedef float f32x4 __attribute__((ext_vector_type(4)));
typedef _Float16 f16x4 __attribute__((ext_vector_type(4)));
typedef unsigned short u16x8 __attribute__((ext_vector_type(8)));
typedef int i32x4 __attribute__((ext_vector_type(4)));

union BF8 { u16x8 u; bf16x8 b; };

#define CN 20000   // rows
#define CE 5000    // hyperedges
#define CD 128     // dim
#define NW 625     // 32-row windows
#define EW 5120    // padded e stride
#define CKS 25     // n-splits in MFMA pass (25 windows = 800 rows each)

// ---------------- K1: fused [H->bits streamer | x@W.T -> p,pT,gTt], roles interleaved (R13 form) ----------------
__global__ __launch_bounds__(256) void k_front(const float* __restrict__ x,
                                               const float* __restrict__ W,
                                               const float* __restrict__ u,
                                               const int* __restrict__ H,
                                               float* __restrict__ p,
                                               u16* __restrict__ pT,
                                               u16* __restrict__ gTt,
                                               u32* __restrict__ bitsT) {
  __shared__ __align__(16) float smem[19200];   // 76.8 KB (h-branch); streamers just allocate it
  int t = threadIdx.x;
  int bid = blockIdx.x;
  int role = bid % 7;
  if (role >= 2) {
    // ---- H streamer: bit j of bitsT[nw][e] = H[nw*32+j][e] (H in {0,1}) ----
    int w = t >> 6, l = t & 63;
    int sb = (bid / 7) * 5 + (role - 2);       // 0..3124
    int task = sb * 4 + w;                     // 0..12499
    int nw = task / 20;
    int seg = task - nw * 20;
    int ebase = seg * 256 + l * 4;
    u32 b0 = 0, b1 = 0, b2 = 0, b3 = 0;
    if (ebase < CE) {                          // CE%4==0: all 4 comps valid
      const int* Hb = H + (size_t)nw * 32 * CE + ebase;
      i32x4 c[8];
#pragma unroll
      for (int j = 0; j < 8; ++j)
        c[j] = __builtin_nontemporal_load((const i32x4*)(Hb + (size_t)j * CE));
#pragma unroll
      for (int r = 0; r < 32; r += 8) {
        i32x4 nx[8];
        if (r + 8 < 32) {
#pragma unroll
          for (int j = 0; j < 8; ++j)
            nx[j] = __builtin_nontemporal_load((const i32x4*)(Hb + (size_t)(r + 8 + j) * CE));
        }
#pragma unroll
        for (int j = 0; j < 8; ++j) {
          b0 |= ((u32)c[j].x) << (r + j);
          b1 |= ((u32)c[j].y) << (r + j);
          b2 |= ((u32)c[j].z) << (r + j);
          b3 |= ((u32)c[j].w) << (r + j);
        }
        if (r + 8 < 32) {
#pragma unroll
          for (int j = 0; j < 8; ++j) c[j] = nx[j];
        }
      }
    }
    uint4 bw; bw.x = b0; bw.y = b1; bw.z = b2; bw.w = b3;
    *(uint4*)(bitsT + (size_t)nw * EW + ebase) = bw;
  } else {
    // ---- h-producer: 16 rows/block, W tile in LDS; p = exp(sc) (shift-free safe) ----
    float* Wl = smem;               // [128][132]
    float* ul = smem + 16896;       // [128]
    float* hl = smem + 17024;       // [16][132]
    float* pl = smem + 19136;       // [16]
    int hb = (bid / 7) * 2 + role;  // 0..1249
    if (t < 128) ul[t] = u[t];
    for (int j = t; j < 128 * 128; j += 256) {
      int d = j >> 7, k = j & 127;
      Wl[d * 132 + k] = W[j];
    }
    __syncthreads();
    int slot = t >> 5;
    int dg = t & 31;
    int r0 = hb * 16 + slot * 2;
    const float* x0 = x + (size_t)r0 * 128;
    const float* x1 = x0 + 128;
    float b0 = 0.f, b1 = 0.f, b2 = 0.f, b3 = 0.f;
    float c0 = 0.f, c1 = 0.f, c2 = 0.f, c3 = 0.f;
#pragma unroll 4
    for (int k = 0; k < 128; k += 4) {
      float4 w0 = *(const float4*)(Wl + dg * 132 + k);
      float4 w1 = *(const float4*)(Wl + (dg + 32) * 132 + k);
      float4 w2 = *(const float4*)(Wl + (dg + 64) * 132 + k);
      float4 w3 = *(const float4*)(Wl + (dg + 96) * 132 + k);
      float4 xa = *(const float4*)(x0 + k);
      float4 xb = *(const float4*)(x1 + k);
      b0 += xa.x * w0.x + xa.y * w0.y + xa.z * w0.z + xa.w * w0.w;
      b1 += xa.x * w1.x + xa.y * w1.y + xa.z * w1.z + xa.w * w1.w;
      b2 += xa.x * w2.x + xa.y * w2.y + xa.z * w2.z + xa.w * w2.w;
      b3 += xa.x * w3.x + xa.y * w3.y + xa.z * w3.z + xa.w * w3.w;
      c0 += xb.x * w0.x + xb.y * w0.y + xb.z * w0.z + xb.w * w0.w;
      c1 += xb.x * w1.x + xb.y * w1.y + xb.z * w1.z + xb.w * w1.w;
      c2 += xb.x * w2.x + xb.y * w2.y + xb.z * w2.z + xb.w * w2.w;
      c3 += xb.x * w3.x + xb.y * w3.y + xb.z * w3.z + xb.w * w3.w;
    }
    int lr0 = slot * 2, lr1 = slot * 2 + 1;
    hl[lr0 * 132 + dg] = b0; hl[lr0 * 132 + dg + 32] = b1;
    hl[lr0 * 132 + dg + 64] = b2; hl[lr0 * 132 + dg + 96] = b3;
    hl[lr1 * 132 + dg] = c0; hl[lr1 * 132 + dg + 32] = c1;
    hl[lr1 * 132 + dg + 64] = c2; hl[lr1 * 132 + dg + 96] = c3;
    float s0 = b0 * ul[dg] + b1 * ul[dg + 32] + b2 * ul[dg + 64] + b3 * ul[dg + 96];
    float s1 = c0 * ul[dg] + c1 * ul[dg + 32] + c2 * ul[dg + 64] + c3 * ul[dg + 96];
#pragma unroll
    for (int off = 16; off; off >>= 1) {
      s0 += __shfl_down(s0, off, 32);
      s1 += __shfl_down(s1, off, 32);
    }
    int nw = hb >> 1;
    int base = (hb & 1) * 16;
    if (dg == 0) {
      float p0 = __expf(s0 * 0.08838834764831845f);
      float p1 = __expf(s1 * 0.08838834764831845f);
      pl[lr0] = p0; pl[lr1] = p1;
      p[r0] = p0; p[r0 + 1] = p1;
      union { __hip_bfloat16 b; u16 s; } cv;
      cv.b = __float2bfloat16(p0); pT[nw * 32 + base + lr0] = cv.s;
      cv.b = __float2bfloat16(p1); pT[nw * 32 + base + lr1] = cv.s;
    }
    __syncthreads();
    int d = t >> 1, ch = t & 1;
    u16x8 v;
#pragma unroll
    for (int i = 0; i < 8; ++i) {
      int r = ch * 8 + i;
      union { __hip_bfloat16 b; u16 s; } cv;
      cv.b = __float2bfloat16(hl[r * 132 + d] * pl[r]);
      v[i] = cv.s;
    }
    *(u16x8*)(gTt + (size_t)nw * 4096 + d * 32 + base + ch * 8) = v;
  }
}

// ---------------- K2: MFMA pass, 256 e's/block; D via p-row MFMA; numpart fp16 ----------------
__global__ __launch_bounds__(256, 2) void k_mm(const u32* __restrict__ bitsT,
                                               const u16* __restrict__ gTt,
                                               const u16* __restrict__ pT,
                                               _Float16* __restrict__ numpart,
                                               float* __restrict__ Dpart) {
  __shared__ u32 wl[256];
  __shared__ __align__(16) u16 gl[128 * 40];
  __shared__ __align__(16) u16 glp[16 * 40];
  int t = threadIdx.x;
  int w = t >> 6, l = t & 63;
  int be = blockIdx.x, ks = blockIdx.y;      // be 0..19, ks 0..24
  int e0 = be * 256;

  for (int j = t; j < 640; j += 256) glp[j] = 0;

  f32x4 acc[4][8];
  f32x4 acc2[4];
#pragma unroll
  for (int s = 0; s < 4; ++s) {
#pragma unroll
    for (int dt = 0; dt < 8; ++dt) acc[s][dt] = (f32x4){0.f, 0.f, 0.f, 0.f};
    acc2[s] = (f32x4){0.f, 0.f, 0.f, 0.f};
  }

  for (int wi = ks * 25; wi < ks * 25 + 25; ++wi) {
    if (t < 64) *(uint4*)&wl[t * 4] = *(const uint4*)(bitsT + (size_t)wi * EW + e0 + t * 4);
    {
      const u16* src = gTt + (size_t)wi * 4096 + (t >> 1) * 32 + (t & 1) * 16;
      u16x8 v0 = *(const u16x8*)src;
      u16x8 v1 = *(const u16x8*)(src + 8);
      u16* dst = gl + (t >> 1) * 40 + (t & 1) * 16;
      *(u16x8*)dst = v0;
      *(u16x8*)(dst + 8) = v1;
    }
    if (t < 4) *(u16x8*)(glp + t * 8) = *(const u16x8*)(pT + wi * 32 + t * 8);
    __syncthreads();
    int rb = (l >> 4) * 8;
    BF8 cva[4];
#pragma unroll
    for (int s = 0; s < 4; ++s) {
      u32 ws = wl[64 * w + 16 * s + (l & 15)];
#pragma unroll
      for (int jj = 0; jj < 8; ++jj)
        cva[s].u[jj] = (u16)(((ws >> (rb + jj)) & 1u) * 0x3F80u);
    }
    bf16x8 bfp = *(const bf16x8*)(glp + (l & 15) * 40 + (l >> 4) * 8);
#pragma unroll
    for (int dt = 0; dt < 8; ++dt) {
      bf16x8 bfr = *(const bf16x8*)(gl + (dt * 16 + (l & 15)) * 40 + (l >> 4) * 8);
      acc[0][dt] = __builtin_amdgcn_mfma_f32_16x16x32_bf16(cva[0].b, bfr, acc[0][dt], 0, 0, 0);
      acc[1][dt] = __builtin_amdgcn_mfma_f32_16x16x32_bf16(cva[1].b, bfr, acc[1][dt], 0, 0, 0);
      acc[2][dt] = __builtin_amdgcn_mfma_f32_16x16x32_bf16(cva[2].b, bfr, acc[2][dt], 0, 0, 0);
      acc[3][dt] = __builtin_amdgcn_mfma_f32_16x16x32_bf16(cva[3].b, bfr, acc[3][dt], 0, 0, 0);
    }
#pragma unroll
    for (int s = 0; s < 4; ++s)
      acc2[s] = __builtin_amdgcn_mfma_f32_16x16x32_bf16(cva[s].b, bfp, acc2[s], 0, 0, 0);
    __syncthreads();
  }
#pragma unroll
  for (int s = 0; s < 4; ++s)
#pragma unroll
    for (int dt = 0; dt < 8; ++dt)
#pragma unroll
      for (int r = 0; r < 4; ++r) {
        int e = e0 + w * 64 + s * 16 + (l >> 4) * 4 + r;
        int d = dt * 16 + (l & 15);
        numpart[((size_t)ks * EW + e) * 128 + d] = (_Float16)acc[s][dt][r];
      }
  if ((l & 15) == 0) {
#pragma unroll
    for (int s = 0; s < 4; ++s)
#pragma unroll
      for (int r = 0; r < 4; ++r) {
        int e = e0 + w * 64 + s * 16 + (l >> 4) * 4 + r;
        Dpart[(size_t)ks * EW + e] = acc2[s][r];
      }
  }
}

// ---------------- K3 (merged, 3 launches total): [A-write by e-range | out0 reduce] ----------------
// 1125 blocks = 9*125: roles 0-3 -> A-write (500 = 20 er x 25 nc), roles 4-8 -> out0 (625).
// A-role computes invD for its 256 e's from Dpart (25.6 KB, L3-hot) -> no k_inv, no race.
__global__ __launch_bounds__(256) void k_last(const _Float16* __restrict__ numpart,
                                              const float* __restrict__ Dpart,
                                              const u32* __restrict__ bitsT,
                                              const float* __restrict__ p,
                                              float* __restrict__ out0,
                                              float* __restrict__ A) {
  __shared__ float pl[800];
  __shared__ __align__(16) float ivq[256];
  int t = threadIdx.x;
  int bid = blockIdx.x;
  int role = bid % 9;
  if (role >= 4) {
    // ---- out0 reduce: one (e, d-quad) cell per thread; D inline (800 B unique/block) ----
    int b = (bid / 9) * 5 + (role - 4);      // 0..624
    int cell = b * 256 + t;                  // < 160000 = 5000 e x 32 quads
    int e = cell >> 5, dq = cell & 31;
    f32x4 s = (f32x4){0.f, 0.f, 0.f, 0.f};
    float D = 0.f;
#pragma unroll
    for (int ks = 0; ks < CKS; ++ks) {
      f16x4 v = *(const f16x4*)(numpart + ((size_t)ks * EW + e) * 128 + dq * 4);
      s += __builtin_convertvector(v, f32x4);
      D += Dpart[(size_t)ks * EW + e];
    }
    float r = 1.0f / D;
    *(f32x4*)(out0 + (size_t)e * 128 + dq * 4) = s * r;
  } else {
    // ---- A-write: block owns e-range [er*256, er*256+256) x n-chunk [nc*800, nc*800+800) ----
    int ab = (bid / 9) * 4 + role;           // 0..499
    int er = ab % 20, nc = ab / 20;          // er 0..19, nc 0..24
    int e0 = er * 256;
    for (int i = t; i < 800; i += 256) pl[i] = p[nc * 800 + i];
    {
      int e = e0 + t;                        // < 5120 (padding -> inf, never stored)
      float D = 0.f;
#pragma unroll
      for (int k2 = 0; k2 < CKS; ++k2) D += Dpart[(size_t)k2 * EW + e];
      ivq[t] = 1.0f / D;
    }
    __syncthreads();
    int q = t & 63, r = t >> 6;              // e-quad 0..63, row-group 0..3
    bool ok = (e0 + q * 4) < CE;             // clamp padding quads (er=19 only)
    float4 iv = *(const float4*)(ivq + q * 4);
    for (int nw2 = 0; nw2 < 25; ++nw2) {
      int nw = nc * 25 + nw2;
      uint4 wv = *(const uint4*)(bitsT + (size_t)nw * EW + e0 + q * 4);
#pragma unroll
      for (int jj = 0; jj < 8; ++jj) {
        int j = jj * 4 + r;                  // row within window
        float pn = pl[nw2 * 32 + j];
        f32x4 o;
        o[0] = ((wv.x >> j) & 1u) ? pn * iv.x : 0.f;
        o[1] = ((wv.y >> j) & 1u) ? pn * iv.y : 0.f;
        o[2] = ((wv.z >> j) & 1u) ? pn * iv.z : 0.f;
        o[3] = ((wv.w >> j) & 1u) ? pn * iv.w : 0.f;
        if (ok)
          __builtin_nontemporal_store(o, (f32x4*)(A + (size_t)(nc * 800 + nw2 * 32 + j) * CE + e0 + q * 4));
      }
    }
  }
}

// ---------------- Fallback (when ws too small): R9 path k_mid + k_aw ----------------
__global__ __launch_bounds__(256) void k_mid(const _Float16* __restrict__ numpart,
                                             const float* __restrict__ Dpart,
                                             float* __restrict__ out0,
                                             float* __restrict__ invD) {
  int t = threadIdx.x;
  int b = blockIdx.x;
  if (b < 20) {
    int e = b * 256 + t;
    float D = 0.f;
#pragma unroll
    for (int ks = 0; ks < CKS; ++ks) D += Dpart[(size_t)ks * EW + e];
    invD[e] = 1.0f / D;
  } else {
    int cell = (b - 20) * 256 + t;
    int e = cell >> 5, dq = cell & 31;
    f32x4 s = (f32x4){0.f, 0.f, 0.f, 0.f};
    float D = 0.f;
#pragma unroll
    for (int ks = 0; ks < CKS; ++ks) {
      f16x4 v = *(const f16x4*)(numpart + ((size_t)ks * EW + e) * 128 + dq * 4);
      s += __builtin_convertvector(v, f32x4);
      D += Dpart[(size_t)ks * EW + e];
    }
    float r = 1.0f / D;
    *(f32x4*)(out0 + (size_t)e * 128 + dq * 4) = s * r;
  }
}

__global__ __launch_bounds__(256) void k_aw(const u32* __restrict__ bitsT,
                                            const float* __restrict__ p,
                                            const float* __restrict__ invD,
                                            float* __restrict__ A) {
  __shared__ u32 wl4[4 * 1280];
  __shared__ float pl[16];
  int t = threadIdx.x;
  int n0 = blockIdx.x * 16;
  int nw = blockIdx.x >> 1;
  int base = (blockIdx.x & 1) * 16;
  for (int idx = t; idx < 1280; idx += 256) {
    uint4 wv = *(const uint4*)(bitsT + (size_t)nw * EW + idx * 4);
    wl4[idx] = wv.x;
    wl4[1280 + idx] = wv.y;
    wl4[2560 + idx] = wv.z;
    wl4[3840 + idx] = wv.w;
  }
  if (t < 16) pl[t] = p[n0 + t];
  __syncthreads();
  for (int q = t; q < 1250; q += 256) {
    u32 wd0 = wl4[q];
    u32 wd1 = wl4[1280 + q];
    u32 wd2 = wl4[2560 + q];
    u32 wd3 = wl4[3840 + q];
    float4 iv = *(const float4*)(invD + q * 4);
#pragma unroll
    for (int no = 0; no < 16; ++no) {
      int bp = base + no;
      float pn = pl[no];
      f32x4 o;
      o[0] = ((wd0 >> bp) & 1u) ? pn * iv.x : 0.f;
      o[1] = ((wd1 >> bp) & 1u) ? pn * iv.y : 0.f;
      o[2] = ((wd2 >> bp) & 1u) ? pn * iv.z : 0.f;
      o[3] = ((wd3 >> bp) & 1u) ? pn * iv.w : 0.f;
      __builtin_nontemporal_store(o, (f32x4*)(A + (size_t)(n0 + no) * CE + q * 4));
    }
  }
}

extern "C" void kernel_launch(void* const* d_in, const int* in_sizes, int n_in,
                              void* d_out, int out_size, void* d_ws, size_t ws_size,
                              hipStream_t stream) {
  const float* x = (const float*)d_in[0];
  const int*   H = (const int*)d_in[1];
  const float* W = (const float*)d_in[2];
  const float* u = (const float*)d_in[3];

  float* out0 = (float*)d_out;               // [E][128]
  float* Aout = out0 + CE * CD;              // [N][E]

  // gTt lives in the (dead-before-last-kernel) A region:
  u16* gTt = (u16*)(Aout + 16500000);        // [625][128][32] bf16 (5 MB)

  float* wsf = (float*)d_ws;
  float* p     = wsf;                        // [20000]
  u16*   pT    = (u16*)(wsf + 20480);        // [625][32] bf16
  float* invD  = wsf + 30720;                // [5120] (fallback only)
  float* Dpart = wsf + 36864;                // [25][5120]
  u32*   bitsT = (u32*)(wsf + 165888);       // [625][5120] u32 = 12.8 MB; ends @ 3,365,888 f

  // merged path needs numpart in d_ws (out0-role reads it while A-roles write A):
  size_t need = (size_t)(3366912 + 8192000) * 4;  // ~46.3 MB
  bool merged = ws_size >= need;
  _Float16* numpart = merged ? (_Float16*)(wsf + 3366912)
                             : (_Float16*)Aout;   // fallback: A region (read before k_aw)

  k_front<<<dim3(4375),   dim3(256), 0, stream>>>(x, W, u, H, p, pT, gTt, bitsT);
  k_mm   <<<dim3(20, 25), dim3(256), 0, stream>>>(bitsT, gTt, pT, numpart, Dpart);
  if (merged) {
    k_last<<<dim3(1125),  dim3(256), 0, stream>>>(numpart, Dpart, bitsT, p, out0, Aout);
  } else {
    k_mid <<<dim3(645),   dim3(256), 0, stream>>>(numpart, Dpart, out0, invD);
    k_aw  <<<dim3(1250),  dim3(256), 0, stream>>>(bitsT, p, invD, Aout);
  }
}

// Round 16
// 243.567 us; speedup vs baseline: 1.0381x; 1.0381x over previous
//
#include <hip/hip_runtime.h>
#include <hip/hip_bf16.h>

typedef unsigned int u32;
typedef unsigned short u16;
typedef __bf16 bf16x8 __attribute__((ext_vector_type(8)));
typedef float f32x4 __attribute__((ext_vector_type(4)));
typedef _Float16 f16x4 __attribute__((ext_vector_type(4)));
typedef unsigned short u16x8 __attribute__((ext_vector_type(8)));
typedef int i32x4 __attribute__((ext_vector_type(4)));

union BF8 { u16x8 u; bf16x8 b; };

#define CN 20000   // rows
#define CE 5000    // hyperedges
#define CD 128     // dim
#define NW 625     // 32-row windows
#define EW 5120    // padded e stride
#define CKS 25     // n-splits in MFMA pass (25 windows = 800 rows each)

// ---------------- K1: fused [H->bits streamer | x@W.T -> p,pT,gTt], roles interleaved ----------------
__global__ __launch_bounds__(256) void k_front(const float* __restrict__ x,
                                               const float* __restrict__ W,
                                               const float* __restrict__ u,
                                               const int* __restrict__ H,
                                               float* __restrict__ p,
                                               u16* __restrict__ pT,
                                               u16* __restrict__ gTt,
                                               u32* __restrict__ bitsT) {
  __shared__ __align__(16) float smem[19200];   // 76.8 KB (h-branch); streamers just allocate it
  int t = threadIdx.x;
  int bid = blockIdx.x;
  int role = bid % 7;
  if (role >= 2) {
    // ---- H streamer: bit j of bitsT[nw][e] = H[nw*32+j][e] (H in {0,1}) ----
    int w = t >> 6, l = t & 63;
    int sb = (bid / 7) * 5 + (role - 2);       // 0..3124
    int task = sb * 4 + w;                     // 0..12499
    int nw = task / 20;
    int seg = task - nw * 20;
    int ebase = seg * 256 + l * 4;
    u32 b0 = 0, b1 = 0, b2 = 0, b3 = 0;
    if (ebase < CE) {                          // CE%4==0: all 4 comps valid
      const int* Hb = H + (size_t)nw * 32 * CE + ebase;
      i32x4 c[8];
#pragma unroll
      for (int j = 0; j < 8; ++j)
        c[j] = __builtin_nontemporal_load((const i32x4*)(Hb + (size_t)j * CE));
#pragma unroll
      for (int r = 0; r < 32; r += 8) {
        i32x4 nx[8];
        if (r + 8 < 32) {
#pragma unroll
          for (int j = 0; j < 8; ++j)
            nx[j] = __builtin_nontemporal_load((const i32x4*)(Hb + (size_t)(r + 8 + j) * CE));
        }
#pragma unroll
        for (int j = 0; j < 8; ++j) {
          b0 |= ((u32)c[j].x) << (r + j);
          b1 |= ((u32)c[j].y) << (r + j);
          b2 |= ((u32)c[j].z) << (r + j);
          b3 |= ((u32)c[j].w) << (r + j);
        }
        if (r + 8 < 32) {
#pragma unroll
          for (int j = 0; j < 8; ++j) c[j] = nx[j];
        }
      }
    }
    uint4 bw; bw.x = b0; bw.y = b1; bw.z = b2; bw.w = b3;
    *(uint4*)(bitsT + (size_t)nw * EW + ebase) = bw;
  } else {
    // ---- h-producer: 16 rows/block, W tile in LDS; p = exp(sc) (shift-free safe) ----
    float* Wl = smem;               // [128][132]
    float* ul = smem + 16896;       // [128]
    float* hl = smem + 17024;       // [16][132]
    float* pl = smem + 19136;       // [16]
    int hb = (bid / 7) * 2 + role;  // 0..1249
    if (t < 128) ul[t] = u[t];
    for (int j = t; j < 128 * 128; j += 256) {
      int d = j >> 7, k = j & 127;
      Wl[d * 132 + k] = W[j];
    }
    __syncthreads();
    int slot = t >> 5;
    int dg = t & 31;
    int r0 = hb * 16 + slot * 2;
    const float* x0 = x + (size_t)r0 * 128;
    const float* x1 = x0 + 128;
    float b0 = 0.f, b1 = 0.f, b2 = 0.f, b3 = 0.f;
    float c0 = 0.f, c1 = 0.f, c2 = 0.f, c3 = 0.f;
#pragma unroll 4
    for (int k = 0; k < 128; k += 4) {
      float4 w0 = *(const float4*)(Wl + dg * 132 + k);
      float4 w1 = *(const float4*)(Wl + (dg + 32) * 132 + k);
      float4 w2 = *(const float4*)(Wl + (dg + 64) * 132 + k);
      float4 w3 = *(const float4*)(Wl + (dg + 96) * 132 + k);
      float4 xa = *(const float4*)(x0 + k);
      float4 xb = *(const float4*)(x1 + k);
      b0 += xa.x * w0.x + xa.y * w0.y + xa.z * w0.z + xa.w * w0.w;
      b1 += xa.x * w1.x + xa.y * w1.y + xa.z * w1.z + xa.w * w1.w;
      b2 += xa.x * w2.x + xa.y * w2.y + xa.z * w2.z + xa.w * w2.w;
      b3 += xa.x * w3.x + xa.y * w3.y + xa.z * w3.z + xa.w * w3.w;
      c0 += xb.x * w0.x + xb.y * w0.y + xb.z * w0.z + xb.w * w0.w;
      c1 += xb.x * w1.x + xb.y * w1.y + xb.z * w1.z + xb.w * w1.w;
      c2 += xb.x * w2.x + xb.y * w2.y + xb.z * w2.z + xb.w * w2.w;
      c3 += xb.x * w3.x + xb.y * w3.y + xb.z * w3.z + xb.w * w3.w;
    }
    int lr0 = slot * 2, lr1 = slot * 2 + 1;
    hl[lr0 * 132 + dg] = b0; hl[lr0 * 132 + dg + 32] = b1;
    hl[lr0 * 132 + dg + 64] = b2; hl[lr0 * 132 + dg + 96] = b3;
    hl[lr1 * 132 + dg] = c0; hl[lr1 * 132 + dg + 32] = c1;
    hl[lr1 * 132 + dg + 64] = c2; hl[lr1 * 132 + dg + 96] = c3;
    float s0 = b0 * ul[dg] + b1 * ul[dg + 32] + b2 * ul[dg + 64] + b3 * ul[dg + 96];
    float s1 = c0 * ul[dg] + c1 * ul[dg + 32] + c2 * ul[dg + 64] + c3 * ul[dg + 96];
#pragma unroll
    for (int off = 16; off; off >>= 1) {
      s0 += __shfl_down(s0, off, 32);
      s1 += __shfl_down(s1, off, 32);
    }
    int nw = hb >> 1;
    int base = (hb & 1) * 16;
    if (dg == 0) {
      float p0 = __expf(s0 * 0.08838834764831845f);
      float p1 = __expf(s1 * 0.08838834764831845f);
      pl[lr0] = p0; pl[lr1] = p1;
      p[r0] = p0; p[r0 + 1] = p1;
      union { __hip_bfloat16 b; u16 s; } cv;
      cv.b = __float2bfloat16(p0); pT[nw * 32 + base + lr0] = cv.s;
      cv.b = __float2bfloat16(p1); pT[nw * 32 + base + lr1] = cv.s;
    }
    __syncthreads();
    int d = t >> 1, ch = t & 1;
    u16x8 v;
#pragma unroll
    for (int i = 0; i < 8; ++i) {
      int r = ch * 8 + i;
      union { __hip_bfloat16 b; u16 s; } cv;
      cv.b = __float2bfloat16(hl[r * 132 + d] * pl[r]);
      v[i] = cv.s;
    }
    *(u16x8*)(gTt + (size_t)nw * 4096 + d * 32 + base + ch * 8) = v;
  }
}

// ---------------- K2: MFMA pass, 256 e's/block; D via p-row MFMA; numpart fp16 ----------------
__global__ __launch_bounds__(256, 2) void k_mm(const u32* __restrict__ bitsT,
                                               const u16* __restrict__ gTt,
                                               const u16* __restrict__ pT,
                                               _Float16* __restrict__ numpart,
                                               float* __restrict__ Dpart) {
  __shared__ u32 wl[256];
  __shared__ __align__(16) u16 gl[128 * 40];
  __shared__ __align__(16) u16 glp[16 * 40];
  int t = threadIdx.x;
  int w = t >> 6, l = t & 63;
  int be = blockIdx.x, ks = blockIdx.y;      // be 0..19, ks 0..24
  int e0 = be * 256;

  for (int j = t; j < 640; j += 256) glp[j] = 0;

  f32x4 acc[4][8];
  f32x4 acc2[4];
#pragma unroll
  for (int s = 0; s < 4; ++s) {
#pragma unroll
    for (int dt = 0; dt < 8; ++dt) acc[s][dt] = (f32x4){0.f, 0.f, 0.f, 0.f};
    acc2[s] = (f32x4){0.f, 0.f, 0.f, 0.f};
  }

  for (int wi = ks * 25; wi < ks * 25 + 25; ++wi) {
    if (t < 64) *(uint4*)&wl[t * 4] = *(const uint4*)(bitsT + (size_t)wi * EW + e0 + t * 4);
    {
      const u16* src = gTt + (size_t)wi * 4096 + (t >> 1) * 32 + (t & 1) * 16;
      u16x8 v0 = *(const u16x8*)src;
      u16x8 v1 = *(const u16x8*)(src + 8);
      u16* dst = gl + (t >> 1) * 40 + (t & 1) * 16;
      *(u16x8*)dst = v0;
      *(u16x8*)(dst + 8) = v1;
    }
    if (t < 4) *(u16x8*)(glp + t * 8) = *(const u16x8*)(pT + wi * 32 + t * 8);
    __syncthreads();
    int rb = (l >> 4) * 8;
    BF8 cva[4];
#pragma unroll
    for (int s = 0; s < 4; ++s) {
      u32 ws = wl[64 * w + 16 * s + (l & 15)];
#pragma unroll
      for (int jj = 0; jj < 8; ++jj)
        cva[s].u[jj] = (u16)(((ws >> (rb + jj)) & 1u) * 0x3F80u);
    }
    bf16x8 bfp = *(const bf16x8*)(glp + (l & 15) * 40 + (l >> 4) * 8);
#pragma unroll
    for (int dt = 0; dt < 8; ++dt) {
      bf16x8 bfr = *(const bf16x8*)(gl + (dt * 16 + (l & 15)) * 40 + (l >> 4) * 8);
      acc[0][dt] = __builtin_amdgcn_mfma_f32_16x16x32_bf16(cva[0].b, bfr, acc[0][dt], 0, 0, 0);
      acc[1][dt] = __builtin_amdgcn_mfma_f32_16x16x32_bf16(cva[1].b, bfr, acc[1][dt], 0, 0, 0);
      acc[2][dt] = __builtin_amdgcn_mfma_f32_16x16x32_bf16(cva[2].b, bfr, acc[2][dt], 0, 0, 0);
      acc[3][dt] = __builtin_amdgcn_mfma_f32_16x16x32_bf16(cva[3].b, bfr, acc[3][dt], 0, 0, 0);
    }
#pragma unroll
    for (int s = 0; s < 4; ++s)
      acc2[s] = __builtin_amdgcn_mfma_f32_16x16x32_bf16(cva[s].b, bfp, acc2[s], 0, 0, 0);
    __syncthreads();
  }
#pragma unroll
  for (int s = 0; s < 4; ++s)
#pragma unroll
    for (int dt = 0; dt < 8; ++dt)
#pragma unroll
      for (int r = 0; r < 4; ++r) {
        int e = e0 + w * 64 + s * 16 + (l >> 4) * 4 + r;
        int d = dt * 16 + (l & 15);
        numpart[((size_t)ks * EW + e) * 128 + d] = (_Float16)acc[s][dt][r];
      }
  if ((l & 15) == 0) {
#pragma unroll
    for (int s = 0; s < 4; ++s)
#pragma unroll
      for (int r = 0; r < 4; ++r) {
        int e = e0 + w * 64 + s * 16 + (l >> 4) * 4 + r;
        Dpart[(size_t)ks * EW + e] = acc2[s][r];
      }
  }
}

// ---------------- K3: invD only (tiny) ----------------
__global__ __launch_bounds__(256) void k_inv(const float* __restrict__ Dpart,
                                             float* __restrict__ invD) {
  int e = blockIdx.x * 256 + threadIdx.x;    // < 5120
  float D = 0.f;
#pragma unroll
  for (int ks = 0; ks < CKS; ++ks) D += Dpart[(size_t)ks * EW + e];
  invD[e] = 1.0f / D;
}

// ---------------- K4 (merged): [out0 reduce | A-write], 3-role interleave ----------------
__global__ __launch_bounds__(256) void k_last(const _Float16* __restrict__ numpart,
                                              const float* __restrict__ Dpart,
                                              const u32* __restrict__ bitsT,
                                              const float* __restrict__ p,
                                              const float* __restrict__ invD,
                                              float* __restrict__ out0,
                                              float* __restrict__ A) {
  __shared__ u32 wl4[4 * 1280];
  __shared__ float pl[16];
  int t = threadIdx.x;
  int bid = blockIdx.x;
  int role = bid % 3;
  if (role == 0) {
    // ---- out0 reduce: one (e, d-quad) cell per thread ----
    int b = bid / 3;
    int cell = b * 256 + t;                  // 0..159999 = 5000 e x 32 quads
    int e = cell >> 5, dq = cell & 31;
    f32x4 s = (f32x4){0.f, 0.f, 0.f, 0.f};
#pragma unroll
    for (int ks = 0; ks < CKS; ++ks) {
      f16x4 v = *(const f16x4*)(numpart + ((size_t)ks * EW + e) * 128 + dq * 4);
      s += __builtin_convertvector(v, f32x4);
    }
    *(f32x4*)(out0 + (size_t)e * 128 + dq * 4) = s * invD[e];
  } else {
    // ---- A-write (global invD) ----
    int ab = (bid / 3) * 2 + (role - 1);     // 0..1249
    int n0 = ab * 16;
    int nw = ab >> 1;
    int base = (ab & 1) * 16;
    for (int idx = t; idx < 1280; idx += 256) {
      uint4 wv = *(const uint4*)(bitsT + (size_t)nw * EW + idx * 4);
      wl4[idx] = wv.x;
      wl4[1280 + idx] = wv.y;
      wl4[2560 + idx] = wv.z;
      wl4[3840 + idx] = wv.w;
    }
    if (t < 16) pl[t] = p[n0 + t];
    __syncthreads();
    for (int q = t; q < 1250; q += 256) {
      u32 wd0 = wl4[q];
      u32 wd1 = wl4[1280 + q];
      u32 wd2 = wl4[2560 + q];
      u32 wd3 = wl4[3840 + q];
      float4 iv = *(const float4*)(invD + q * 4);
#pragma unroll
      for (int no = 0; no < 16; ++no) {
        int bp = base + no;
        float pn = pl[no];
        f32x4 o;
        o[0] = ((wd0 >> bp) & 1u) ? pn * iv.x : 0.f;
        o[1] = ((wd1 >> bp) & 1u) ? pn * iv.y : 0.f;
        o[2] = ((wd2 >> bp) & 1u) ? pn * iv.z : 0.f;
        o[3] = ((wd3 >> bp) & 1u) ? pn * iv.w : 0.f;
        __builtin_nontemporal_store(o, (f32x4*)(A + (size_t)(n0 + no) * CE + q * 4));
      }
    }
  }
}

// ---------------- Fallback (when ws too small): k_mid + k_aw ----------------
__global__ __launch_bounds__(256) void k_mid(const _Float16* __restrict__ numpart,
                                             const float* __restrict__ Dpart,
                                             float* __restrict__ out0,
                                             float* __restrict__ invD) {
  int t = threadIdx.x;
  int b = blockIdx.x;
  if (b < 20) {
    int e = b * 256 + t;
    float D = 0.f;
#pragma unroll
    for (int ks = 0; ks < CKS; ++ks) D += Dpart[(size_t)ks * EW + e];
    invD[e] = 1.0f / D;
  } else {
    int cell = (b - 20) * 256 + t;
    int e = cell >> 5, dq = cell & 31;
    f32x4 s = (f32x4){0.f, 0.f, 0.f, 0.f};
    float D = 0.f;
#pragma unroll
    for (int ks = 0; ks < CKS; ++ks) {
      f16x4 v = *(const f16x4*)(numpart + ((size_t)ks * EW + e) * 128 + dq * 4);
      s += __builtin_convertvector(v, f32x4);
      D += Dpart[(size_t)ks * EW + e];
    }
    float r = 1.0f / D;
    *(f32x4*)(out0 + (size_t)e * 128 + dq * 4) = s * r;
  }
}

__global__ __launch_bounds__(256) void k_aw(const u32* __restrict__ bitsT,
                                            const float* __restrict__ p,
                                            const float* __restrict__ invD,
                                            float* __restrict__ A) {
  __shared__ u32 wl4[4 * 1280];
  __shared__ float pl[16];
  int t = threadIdx.x;
  int n0 = blockIdx.x * 16;
  int nw = blockIdx.x >> 1;
  int base = (blockIdx.x & 1) * 16;
  for (int idx = t; idx < 1280; idx += 256) {
    uint4 wv = *(const uint4*)(bitsT + (size_t)nw * EW + idx * 4);
    wl4[idx] = wv.x;
    wl4[1280 + idx] = wv.y;
    wl4[2560 + idx] = wv.z;
    wl4[3840 + idx] = wv.w;
  }
  if (t < 16) pl[t] = p[n0 + t];
  __syncthreads();
  for (int q = t; q < 1250; q += 256) {
    u32 wd0 = wl4[q];
    u32 wd1 = wl4[1280 + q];
    u32 wd2 = wl4[2560 + q];
    u32 wd3 = wl4[3840 + q];
    float4 iv = *(const float4*)(invD + q * 4);
#pragma unroll
    for (int no = 0; no < 16; ++no) {
      int bp = base + no;
      float pn = pl[no];
      f32x4 o;
      o[0] = ((wd0 >> bp) & 1u) ? pn * iv.x : 0.f;
      o[1] = ((wd1 >> bp) & 1u) ? pn * iv.y : 0.f;
      o[2] = ((wd2 >> bp) & 1u) ? pn * iv.z : 0.f;
      o[3] = ((wd3 >> bp) & 1u) ? pn * iv.w : 0.f;
      __builtin_nontemporal_store(o, (f32x4*)(A + (size_t)(n0 + no) * CE + q * 4));
    }
  }
}

extern "C" void kernel_launch(void* const* d_in, const int* in_sizes, int n_in,
                              void* d_out, int out_size, void* d_ws, size_t ws_size,
                              hipStream_t stream) {
  const float* x = (const float*)d_in[0];
  const int*   H = (const int*)d_in[1];
  const float* W = (const float*)d_in[2];
  const float* u = (const float*)d_in[3];

  float* out0 = (float*)d_out;               // [E][128]
  float* Aout = out0 + CE * CD;              // [N][E]

  // gTt lives in the (dead-before-last-kernel) A region:
  u16* gTt = (u16*)(Aout + 16500000);        // [625][128][32] bf16 (5 MB)

  float* wsf = (float*)d_ws;
  float* p     = wsf;                        // [20000]
  u16*   pT    = (u16*)(wsf + 20480);        // [625][32] bf16
  float* invD  = wsf + 30720;                // [5120]
  float* Dpart = wsf + 36864;                // [25][5120]
  u32*   bitsT = (u32*)(wsf + 165888);       // [625][5120] u32 = 12.8 MB; ends @ 3,365,888 f

  // merged path needs numpart in d_ws (out0-role reads it while A-roles write A):
  size_t need = (size_t)(3366912 + 8192000) * 4;  // ~46.3 MB
  bool merged = ws_size >= need;
  _Float16* numpart = merged ? (_Float16*)(wsf + 3366912)
                             : (_Float16*)Aout;   // fallback: A region (read before k_aw)

  k_front<<<dim3(4375),   dim3(256), 0, stream>>>(x, W, u, H, p, pT, gTt, bitsT);
  k_mm   <<<dim3(20, 25), dim3(256), 0, stream>>>(bitsT, gTt, pT, numpart, Dpart);
  if (merged) {
    k_inv <<<dim3(20),    dim3(256), 0, stream>>>(Dpart, invD);
    k_last<<<dim3(1875),  dim3(256), 0, stream>>>(numpart, Dpart, bitsT, p, invD, out0, Aout);
  } else {
    k_mid <<<dim3(645),   dim3(256), 0, stream>>>(numpart, Dpart, out0, invD);
    k_aw  <<<dim3(1250),  dim3(256), 0, stream>>>(bitsT, p, invD, Aout);
  }
}